// Round 8
// baseline (417.095 us; speedup 1.0000x reference)
//
#include <hip/hip_runtime.h>
#include <math.h>

#define NLV 16
#define TBL (1u << 19)
#define HMASK (TBL - 1u)
#define PRIME1 2654435761u

#define BINSHIFT 7                   // 128 x 128 spatial bins
#define BINW (1 << BINSHIFT)
#define NBINS (BINW * BINW)

struct Scales { float s[NLV]; };

__device__ __forceinline__ int point_bin(float2 p) {
    int bx = (int)(p.x * (float)BINW);
    int by = (int)(p.y * (float)BINW);
    return (by << BINSHIFT) + bx;
}

// ---- pass 1: per-bin histogram, R replicas keyed by blockIdx%R ----
// blockIdx%8 ~ XCD id (round-robin dispatch) -> each replica's counter
// lines stay in one XCD's L2: cuts cross-XCD atomic ping-pong ~8x.
__global__ void hist_kernel(const float2* __restrict__ pts, int* __restrict__ hist,
                            int N, int rmask) {
    int i = blockIdx.x * 256 + threadIdx.x;
    if (i >= N) return;
    int r = blockIdx.x & rmask;
    atomicAdd(&hist[r * NBINS + point_bin(pts[i])], 1);
}

// ---- pass 2: linear exclusive scan over R*NBINS counters (1 block) ----
__global__ __launch_bounds__(1024) void scan_kernel(int* __restrict__ hist, int total) {
    __shared__ int partials[1024];
    int tid = threadIdx.x;
    int cnt = total / 1024;
    int base = tid * cnt;
    int sum = 0;
    for (int k = 0; k < cnt; ++k) sum += hist[base + k];
    partials[tid] = sum;
    __syncthreads();
    for (int off = 1; off < 1024; off <<= 1) {
        int t = (tid >= off) ? partials[tid - off] : 0;
        __syncthreads();
        partials[tid] += t;
        __syncthreads();
    }
    int run = partials[tid] - sum;    // exclusive base for this thread's chunk
    for (int k = 0; k < cnt; ++k) {   // re-read (avoids 128-deep reg array)
        int v = hist[base + k];
        hist[base + k] = run;
        run += v;
    }
}

// ---- pass 3: scatter indices; replicated cursors (in-place bases) ----
__global__ void scatter_kernel(const float2* __restrict__ pts, int* __restrict__ cur,
                               int* __restrict__ sidx, int N, int rmask) {
    int i = blockIdx.x * 256 + threadIdx.x;
    if (i >= N) return;
    int r = blockIdx.x & rmask;
    int pos = atomicAdd(&cur[r * NBINS + point_bin(pts[i])], 1);
    sidx[pos] = i;
}

// ---- main kernel: 2 sorted points per thread ----
// W1/W2 s_loads shared by both points (halves per-point SMEM sequencing),
// 2x FMA ILP per wait. Gathers for both points issue back-to-back per level.
__global__ __launch_bounds__(256, 3) void hashgrid_mlp_kernel(
    const float2* __restrict__ pts,
    const float2* __restrict__ table,   // [16][524288] float2
    const int*    __restrict__ sidx,    // bin-sorted point indices
    const float*  __restrict__ W1,      // [64][32]
    const float*  __restrict__ W2,      // [3][64]
    float* __restrict__ out,            // [N][3]
    int N, Scales sc)
{
    int j = (blockIdx.x * 256 + threadIdx.x) * 2;
    if (j >= N) return;
    int iA = sidx[j];
    int iB = sidx[j + 1];

    float2 pA = pts[iA];
    float2 pB = pts[iB];
    float encA[32], encB[32];

#pragma unroll
    for (int l = 0; l < NLV; ++l) {
        float s = sc.s[l];
        const float2* tl = table + (size_t)l * TBL;

        float pxA = pA.x * s, pyA = pA.y * s;
        float pxB = pB.x * s, pyB = pB.y * s;
        float fpxA = floorf(pxA), fpyA = floorf(pyA);
        float fpxB = floorf(pxB), fpyB = floorf(pyB);
        float fxA = pxA - fpxA, fyA = pyA - fpyA;
        float fxB = pxB - fpxB, fyB = pyB - fpyB;
        unsigned bxA = (unsigned)(int)fpxA, byA = (unsigned)(int)fpyA;
        unsigned bxB = (unsigned)(int)fpxB, byB = (unsigned)(int)fpyB;
        unsigned hy0A = byA * PRIME1, hy1A = hy0A + PRIME1;
        unsigned hy0B = byB * PRIME1, hy1B = hy0B + PRIME1;

        float2 f00A = tl[( bxA       ^ hy0A) & HMASK];
        float2 f01A = tl[( bxA       ^ hy1A) & HMASK];
        float2 f10A = tl[((bxA + 1u) ^ hy0A) & HMASK];
        float2 f11A = tl[((bxA + 1u) ^ hy1A) & HMASK];
        float2 f00B = tl[( bxB       ^ hy0B) & HMASK];
        float2 f01B = tl[( bxB       ^ hy1B) & HMASK];
        float2 f10B = tl[((bxB + 1u) ^ hy0B) & HMASK];
        float2 f11B = tl[((bxB + 1u) ^ hy1B) & HMASK];

        float gxA = 1.f - fxA, gyA = 1.f - fyA;
        float w00A = gxA * gyA, w01A = gxA * fyA, w10A = fxA * gyA, w11A = fxA * fyA;
        encA[2*l]   = w00A*f00A.x + w01A*f01A.x + w10A*f10A.x + w11A*f11A.x;
        encA[2*l+1] = w00A*f00A.y + w01A*f01A.y + w10A*f10A.y + w11A*f11A.y;

        float gxB = 1.f - fxB, gyB = 1.f - fyB;
        float w00B = gxB * gyB, w01B = gxB * fyB, w10B = fxB * gyB, w11B = fxB * fyB;
        encB[2*l]   = w00B*f00B.x + w01B*f01B.x + w10B*f10B.x + w11B*f11B.x;
        encB[2*l+1] = w00B*f00B.y + w01B*f01B.y + w10B*f10B.y + w11B*f11B.y;
    }

    float oA0 = 0.f, oA1 = 0.f, oA2 = 0.f;
    float oB0 = 0.f, oB1 = 0.f, oB2 = 0.f;
#pragma unroll
    for (int n = 0; n < 64; ++n) {
        float hA = 0.f, hB = 0.f;
#pragma unroll
        for (int k = 0; k < 32; ++k) {
            float w = W1[n*32 + k];          // uniform -> s_load, shared A/B
            hA = fmaf(encA[k], w, hA);
            hB = fmaf(encB[k], w, hB);
        }
        hA = fmaxf(hA, 0.f);
        hB = fmaxf(hB, 0.f);
        float w20 = W2[n], w21 = W2[64 + n], w22 = W2[128 + n];
        oA0 = fmaf(hA, w20, oA0); oA1 = fmaf(hA, w21, oA1); oA2 = fmaf(hA, w22, oA2);
        oB0 = fmaf(hB, w20, oB0); oB1 = fmaf(hB, w21, oB1); oB2 = fmaf(hB, w22, oB2);
    }
    out[3*iA + 0] = oA0; out[3*iA + 1] = oA1; out[3*iA + 2] = oA2;
    out[3*iB + 0] = oB0; out[3*iB + 1] = oB1; out[3*iB + 2] = oB2;
}

// ---- fallback (round-1) if ws too small for the sort ----
__global__ __launch_bounds__(256, 4) void hashgrid_mlp_fallback(
    const float2* __restrict__ pts, const float2* __restrict__ table,
    const float* __restrict__ W1, const float* __restrict__ W2,
    float* __restrict__ out, int N, Scales sc)
{
    int i = blockIdx.x * 256 + threadIdx.x;
    if (i >= N) return;
    float2 p = pts[i];
    float enc[32];
#pragma unroll
    for (int l = 0; l < NLV; ++l) {
        float s = sc.s[l];
        float px = p.x * s, py = p.y * s;
        float fpx = floorf(px), fpy = floorf(py);
        float fx = px - fpx, fy = py - fpy;
        unsigned bx = (unsigned)(int)fpx, by = (unsigned)(int)fpy;
        unsigned hy0 = by * PRIME1, hy1 = hy0 + PRIME1;
        const float2* tl = table + (size_t)l * TBL;
        float2 f00 = tl[( bx       ^ hy0) & HMASK];
        float2 f01 = tl[( bx       ^ hy1) & HMASK];
        float2 f10 = tl[((bx + 1u) ^ hy0) & HMASK];
        float2 f11 = tl[((bx + 1u) ^ hy1) & HMASK];
        float gx = 1.f - fx, gy = 1.f - fy;
        float w00 = gx * gy, w01 = gx * fy, w10 = fx * gy, w11 = fx * fy;
        enc[2*l]   = w00*f00.x + w01*f01.x + w10*f10.x + w11*f11.x;
        enc[2*l+1] = w00*f00.y + w01*f01.y + w10*f10.y + w11*f11.y;
    }
    float o0 = 0.f, o1 = 0.f, o2 = 0.f;
#pragma unroll
    for (int n = 0; n < 64; ++n) {
        float h = 0.f;
#pragma unroll
        for (int k = 0; k < 32; ++k) h = fmaf(enc[k], W1[n*32 + k], h);
        h = fmaxf(h, 0.f);
        o0 = fmaf(h, W2[n], o0); o1 = fmaf(h, W2[64 + n], o1); o2 = fmaf(h, W2[128 + n], o2);
    }
    out[3*i] = o0; out[3*i + 1] = o1; out[3*i + 2] = o2;
}

extern "C" void kernel_launch(void* const* d_in, const int* in_sizes, int n_in,
                              void* d_out, int out_size, void* d_ws, size_t ws_size,
                              hipStream_t stream) {
    const float2* pts   = (const float2*)d_in[0];
    const float2* table = (const float2*)d_in[1];
    const float*  W1    = (const float*)d_in[2];
    const float*  W2    = (const float*)d_in[3];
    float* out = (float*)d_out;
    int N = in_sizes[0] / 2;

    // Replicate numpy: np.floor(16 * 1.447269237440378 ** arange(16)).astype(f32)
    // (level 15 is a floor boundary: 4095, NOT 4096 — host pow matches numpy).
    Scales sc;
    for (int l = 0; l < NLV; ++l)
        sc.s[l] = (float)floor(16.0 * pow(1.447269237440378, (double)l));

    int blocks = (N + 255) / 256;
    int R = 8;                                        // replica count (pow2)
    size_t need = ((size_t)R * NBINS + N) * sizeof(int);
    if (ws_size < need) { R = 1; need = ((size_t)NBINS + N) * sizeof(int); }

    if (ws_size >= need && N % 2 == 0) {
        int* hist = (int*)d_ws;          // R*NBINS counters -> scanned bases -> cursors
        int* sidx = hist + R * NBINS;    // N sorted indices
        hipMemsetAsync(hist, 0, (size_t)R * NBINS * sizeof(int), stream);
        hipLaunchKernelGGL(hist_kernel,    dim3(blocks), dim3(256),  0, stream,
                           pts, hist, N, R - 1);
        hipLaunchKernelGGL(scan_kernel,    dim3(1),      dim3(1024), 0, stream,
                           hist, R * NBINS);
        hipLaunchKernelGGL(scatter_kernel, dim3(blocks), dim3(256),  0, stream,
                           pts, hist, sidx, N, R - 1);
        int mblocks = (N / 2 + 255) / 256;
        hipLaunchKernelGGL(hashgrid_mlp_kernel, dim3(mblocks), dim3(256), 0, stream,
                           pts, table, sidx, W1, W2, out, N, sc);
    } else {
        hipLaunchKernelGGL(hashgrid_mlp_fallback, dim3(blocks), dim3(256), 0, stream,
                           pts, table, W1, W2, out, N, sc);
    }
}

// Round 9
// 257.805 us; speedup vs baseline: 1.6179x; 1.6179x over previous
//
#include <hip/hip_runtime.h>
#include <math.h>

#define NLV 16
#define TBL (1u << 19)
#define HMASK (TBL - 1u)
#define PRIME1 2654435761u

#define BINSHIFT 7                   // 128 x 128 spatial bins
#define BINW (1 << BINSHIFT)
#define NBINS (BINW * BINW)

struct Scales { float s[NLV]; };

__device__ __forceinline__ int point_bin(float2 p) {
    int bx = (int)(p.x * (float)BINW);
    int by = (int)(p.y * (float)BINW);
    return (by << BINSHIFT) + bx;
}

// ---- pass 1: per-bin histogram, R replicas keyed by blockIdx%R ----
__global__ void hist_kernel(const float2* __restrict__ pts, int* __restrict__ hist,
                            int N, int rmask) {
    int i = blockIdx.x * 256 + threadIdx.x;
    if (i >= N) return;
    int r = blockIdx.x & rmask;
    atomicAdd(&hist[r * NBINS + point_bin(pts[i])], 1);
}

// ---- pass 2: coalesced single-block exclusive scan (shuffle-based) ----
// R8 failure: 128-int serial per-thread chunks, uncoalesced, 196 us.
// Now: per 4096-int tile, each thread scans one int4; wave-inclusive scan
// of thread sums via shfl_up; wave totals scanned by wave 0; carry chains
// tiles. total must be a multiple of 4096 (131072 or 16384: both are).
__global__ __launch_bounds__(1024) void scan_kernel(int* __restrict__ hist, int total) {
    __shared__ int wsum[16];
    int tid = threadIdx.x;
    int lane = tid & 63, wid = tid >> 6;
    int carry = 0;
    int4* h4 = (int4*)hist;
    int tiles = total >> 12;
    for (int t = 0; t < tiles; ++t) {
        int4 v = h4[(t << 10) + tid];          // coalesced 16 B/lane
        int tsum = v.x + v.y + v.z + v.w;
        int x = tsum;
#pragma unroll
        for (int off = 1; off < 64; off <<= 1) {
            int y = __shfl_up(x, off, 64);
            if (lane >= off) x += y;
        }
        if (lane == 63) wsum[wid] = x;
        __syncthreads();
        if (wid == 0) {
            int s = (lane < 16) ? wsum[lane] : 0;
#pragma unroll
            for (int off = 1; off < 16; off <<= 1) {
                int y = __shfl_up(s, off, 64);
                if (lane >= off) s += y;
            }
            if (lane < 16) wsum[lane] = s;     // inclusive scan of wave sums
        }
        __syncthreads();
        int waveoff = (wid == 0) ? 0 : wsum[wid - 1];
        int base = carry + waveoff + (x - tsum);  // exclusive base for this int4
        int4 e;
        e.x = base;
        e.y = base + v.x;
        e.z = e.y + v.y;
        e.w = e.z + v.z;
        h4[(t << 10) + tid] = e;
        carry += wsum[15];                     // block total of this tile
        __syncthreads();                       // wsum reused next tile
    }
}

// ---- pass 3: scatter indices; replicated cursors (in-place bases) ----
__global__ void scatter_kernel(const float2* __restrict__ pts, int* __restrict__ cur,
                               int* __restrict__ sidx, int N, int rmask) {
    int i = blockIdx.x * 256 + threadIdx.x;
    if (i >= N) return;
    int r = blockIdx.x & rmask;
    int pos = atomicAdd(&cur[r * NBINS + point_bin(pts[i])], 1);
    sidx[pos] = i;
}

// ---- main kernel: 2 sorted points per thread ----
__global__ __launch_bounds__(256, 3) void hashgrid_mlp_kernel(
    const float2* __restrict__ pts,
    const float2* __restrict__ table,   // [16][524288] float2
    const int*    __restrict__ sidx,    // bin-sorted point indices
    const float*  __restrict__ W1,      // [64][32]
    const float*  __restrict__ W2,      // [3][64]
    float* __restrict__ out,            // [N][3]
    int N, Scales sc)
{
    int j = (blockIdx.x * 256 + threadIdx.x) * 2;
    if (j >= N) return;
    int iA = sidx[j];
    int iB = sidx[j + 1];

    float2 pA = pts[iA];
    float2 pB = pts[iB];
    float encA[32], encB[32];

#pragma unroll
    for (int l = 0; l < NLV; ++l) {
        float s = sc.s[l];
        const float2* tl = table + (size_t)l * TBL;

        float pxA = pA.x * s, pyA = pA.y * s;
        float pxB = pB.x * s, pyB = pB.y * s;
        float fpxA = floorf(pxA), fpyA = floorf(pyA);
        float fpxB = floorf(pxB), fpyB = floorf(pyB);
        float fxA = pxA - fpxA, fyA = pyA - fpyA;
        float fxB = pxB - fpxB, fyB = pyB - fpyB;
        unsigned bxA = (unsigned)(int)fpxA, byA = (unsigned)(int)fpyA;
        unsigned bxB = (unsigned)(int)fpxB, byB = (unsigned)(int)fpyB;
        unsigned hy0A = byA * PRIME1, hy1A = hy0A + PRIME1;
        unsigned hy0B = byB * PRIME1, hy1B = hy0B + PRIME1;

        float2 f00A = tl[( bxA       ^ hy0A) & HMASK];
        float2 f01A = tl[( bxA       ^ hy1A) & HMASK];
        float2 f10A = tl[((bxA + 1u) ^ hy0A) & HMASK];
        float2 f11A = tl[((bxA + 1u) ^ hy1A) & HMASK];
        float2 f00B = tl[( bxB       ^ hy0B) & HMASK];
        float2 f01B = tl[( bxB       ^ hy1B) & HMASK];
        float2 f10B = tl[((bxB + 1u) ^ hy0B) & HMASK];
        float2 f11B = tl[((bxB + 1u) ^ hy1B) & HMASK];

        float gxA = 1.f - fxA, gyA = 1.f - fyA;
        float w00A = gxA * gyA, w01A = gxA * fyA, w10A = fxA * gyA, w11A = fxA * fyA;
        encA[2*l]   = w00A*f00A.x + w01A*f01A.x + w10A*f10A.x + w11A*f11A.x;
        encA[2*l+1] = w00A*f00A.y + w01A*f01A.y + w10A*f10A.y + w11A*f11A.y;

        float gxB = 1.f - fxB, gyB = 1.f - fyB;
        float w00B = gxB * gyB, w01B = gxB * fyB, w10B = fxB * gyB, w11B = fxB * fyB;
        encB[2*l]   = w00B*f00B.x + w01B*f01B.x + w10B*f10B.x + w11B*f11B.x;
        encB[2*l+1] = w00B*f00B.y + w01B*f01B.y + w10B*f10B.y + w11B*f11B.y;
    }

    float oA0 = 0.f, oA1 = 0.f, oA2 = 0.f;
    float oB0 = 0.f, oB1 = 0.f, oB2 = 0.f;
#pragma unroll
    for (int n = 0; n < 64; ++n) {
        float hA = 0.f, hB = 0.f;
#pragma unroll
        for (int k = 0; k < 32; ++k) {
            float w = W1[n*32 + k];          // uniform -> s_load, shared A/B
            hA = fmaf(encA[k], w, hA);
            hB = fmaf(encB[k], w, hB);
        }
        hA = fmaxf(hA, 0.f);
        hB = fmaxf(hB, 0.f);
        float w20 = W2[n], w21 = W2[64 + n], w22 = W2[128 + n];
        oA0 = fmaf(hA, w20, oA0); oA1 = fmaf(hA, w21, oA1); oA2 = fmaf(hA, w22, oA2);
        oB0 = fmaf(hB, w20, oB0); oB1 = fmaf(hB, w21, oB1); oB2 = fmaf(hB, w22, oB2);
    }
    out[3*iA + 0] = oA0; out[3*iA + 1] = oA1; out[3*iA + 2] = oA2;
    out[3*iB + 0] = oB0; out[3*iB + 1] = oB1; out[3*iB + 2] = oB2;
}

// ---- fallback (round-1) if ws too small for the sort ----
__global__ __launch_bounds__(256, 4) void hashgrid_mlp_fallback(
    const float2* __restrict__ pts, const float2* __restrict__ table,
    const float* __restrict__ W1, const float* __restrict__ W2,
    float* __restrict__ out, int N, Scales sc)
{
    int i = blockIdx.x * 256 + threadIdx.x;
    if (i >= N) return;
    float2 p = pts[i];
    float enc[32];
#pragma unroll
    for (int l = 0; l < NLV; ++l) {
        float s = sc.s[l];
        float px = p.x * s, py = p.y * s;
        float fpx = floorf(px), fpy = floorf(py);
        float fx = px - fpx, fy = py - fpy;
        unsigned bx = (unsigned)(int)fpx, by = (unsigned)(int)fpy;
        unsigned hy0 = by * PRIME1, hy1 = hy0 + PRIME1;
        const float2* tl = table + (size_t)l * TBL;
        float2 f00 = tl[( bx       ^ hy0) & HMASK];
        float2 f01 = tl[( bx       ^ hy1) & HMASK];
        float2 f10 = tl[((bx + 1u) ^ hy0) & HMASK];
        float2 f11 = tl[((bx + 1u) ^ hy1) & HMASK];
        float gx = 1.f - fx, gy = 1.f - fy;
        float w00 = gx * gy, w01 = gx * fy, w10 = fx * gy, w11 = fx * fy;
        enc[2*l]   = w00*f00.x + w01*f01.x + w10*f10.x + w11*f11.x;
        enc[2*l+1] = w00*f00.y + w01*f01.y + w10*f10.y + w11*f11.y;
    }
    float o0 = 0.f, o1 = 0.f, o2 = 0.f;
#pragma unroll
    for (int n = 0; n < 64; ++n) {
        float h = 0.f;
#pragma unroll
        for (int k = 0; k < 32; ++k) h = fmaf(enc[k], W1[n*32 + k], h);
        h = fmaxf(h, 0.f);
        o0 = fmaf(h, W2[n], o0); o1 = fmaf(h, W2[64 + n], o1); o2 = fmaf(h, W2[128 + n], o2);
    }
    out[3*i] = o0; out[3*i + 1] = o1; out[3*i + 2] = o2;
}

extern "C" void kernel_launch(void* const* d_in, const int* in_sizes, int n_in,
                              void* d_out, int out_size, void* d_ws, size_t ws_size,
                              hipStream_t stream) {
    const float2* pts   = (const float2*)d_in[0];
    const float2* table = (const float2*)d_in[1];
    const float*  W1    = (const float*)d_in[2];
    const float*  W2    = (const float*)d_in[3];
    float* out = (float*)d_out;
    int N = in_sizes[0] / 2;

    // Replicate numpy: np.floor(16 * 1.447269237440378 ** arange(16)).astype(f32)
    // (level 15 is a floor boundary: 4095, NOT 4096 — host pow matches numpy).
    Scales sc;
    for (int l = 0; l < NLV; ++l)
        sc.s[l] = (float)floor(16.0 * pow(1.447269237440378, (double)l));

    int blocks = (N + 255) / 256;
    int R = 8;                                        // replica count (pow2)
    size_t need = ((size_t)R * NBINS + N) * sizeof(int);
    if (ws_size < need) { R = 1; need = ((size_t)NBINS + N) * sizeof(int); }

    if (ws_size >= need && N % 2 == 0) {
        int* hist = (int*)d_ws;          // R*NBINS counters -> scanned bases -> cursors
        int* sidx = hist + R * NBINS;    // N sorted indices
        hipMemsetAsync(hist, 0, (size_t)R * NBINS * sizeof(int), stream);
        hipLaunchKernelGGL(hist_kernel,    dim3(blocks), dim3(256),  0, stream,
                           pts, hist, N, R - 1);
        hipLaunchKernelGGL(scan_kernel,    dim3(1),      dim3(1024), 0, stream,
                           hist, R * NBINS);
        hipLaunchKernelGGL(scatter_kernel, dim3(blocks), dim3(256),  0, stream,
                           pts, hist, sidx, N, R - 1);
        int mblocks = (N / 2 + 255) / 256;
        hipLaunchKernelGGL(hashgrid_mlp_kernel, dim3(mblocks), dim3(256), 0, stream,
                           pts, table, sidx, W1, W2, out, N, sc);
    } else {
        hipLaunchKernelGGL(hashgrid_mlp_fallback, dim3(blocks), dim3(256), 0, stream,
                           pts, table, W1, W2, out, N, sc);
    }
}

// Round 10
// 214.687 us; speedup vs baseline: 1.9428x; 1.2008x over previous
//
#include <hip/hip_runtime.h>
#include <math.h>

#define NLV 16
#define TBL (1u << 19)
#define HMASK (TBL - 1u)
#define PRIME1 2654435761u

#define BINSHIFT 7                   // 128 x 128 spatial bins
#define BINW (1 << BINSHIFT)
#define NBINS (BINW * BINW)

struct Scales { float s[NLV]; };

__device__ __forceinline__ int point_bin(float2 p) {
    int bx = (int)(p.x * (float)BINW);
    int by = (int)(p.y * (float)BINW);
    return (by << BINSHIFT) + bx;
}

// ---- pass 1: per-bin histogram, R replicas keyed by blockIdx%R ----
__global__ void hist_kernel(const float2* __restrict__ pts, int* __restrict__ hist,
                            int N, int rmask) {
    int i = blockIdx.x * 256 + threadIdx.x;
    if (i >= N) return;
    int r = blockIdx.x & rmask;
    atomicAdd(&hist[r * NBINS + point_bin(pts[i])], 1);
}

// ---- S1: binsum[bin] = sum over replicas (coalesced per r-slice) ----
__global__ void binsum_kernel(const int* __restrict__ hist, int* __restrict__ binsum,
                              int R) {
    int b = blockIdx.x * 256 + threadIdx.x;
    if (b >= NBINS) return;
    int s = 0;
    for (int r = 0; r < R; ++r) s += hist[r * NBINS + b];
    binsum[b] = s;
}

// ---- S2: single-block exclusive scan (verified in R9), now only 16K ints ----
__global__ __launch_bounds__(1024) void scan_kernel(int* __restrict__ data, int total) {
    __shared__ int wsum[16];
    int tid = threadIdx.x;
    int lane = tid & 63, wid = tid >> 6;
    int carry = 0;
    int4* h4 = (int4*)data;
    int tiles = total >> 12;
    for (int t = 0; t < tiles; ++t) {
        int4 v = h4[(t << 10) + tid];          // coalesced 16 B/lane
        int tsum = v.x + v.y + v.z + v.w;
        int x = tsum;
#pragma unroll
        for (int off = 1; off < 64; off <<= 1) {
            int y = __shfl_up(x, off, 64);
            if (lane >= off) x += y;
        }
        if (lane == 63) wsum[wid] = x;
        __syncthreads();
        if (wid == 0) {
            int s = (lane < 16) ? wsum[lane] : 0;
#pragma unroll
            for (int off = 1; off < 16; off <<= 1) {
                int y = __shfl_up(s, off, 64);
                if (lane >= off) s += y;
            }
            if (lane < 16) wsum[lane] = s;     // inclusive scan of wave sums
        }
        __syncthreads();
        int waveoff = (wid == 0) ? 0 : wsum[wid - 1];
        int base = carry + waveoff + (x - tsum);  // exclusive base for this int4
        int4 e;
        e.x = base;
        e.y = base + v.x;
        e.z = e.y + v.y;
        e.w = e.z + v.z;
        h4[(t << 10) + tid] = e;
        carry += wsum[15];
        __syncthreads();
    }
}

// ---- S3: expand bin bases into replica cursors, BIN-MAJOR order ----
// cur[r][bin] = binbase[bin] + sum_{r'<r} hist[r'][bin]
// -> final sidx is bin-major (full 64 pts/bin density, R7 locality),
//    replica only breaks ties within a bin.
__global__ void cursor_kernel(int* __restrict__ hist, const int* __restrict__ binbase,
                              int R) {
    int b = blockIdx.x * 256 + threadIdx.x;
    if (b >= NBINS) return;
    int run = binbase[b];
    for (int r = 0; r < R; ++r) {
        int v = hist[r * NBINS + b];
        hist[r * NBINS + b] = run;
        run += v;
    }
}

// ---- pass 3: scatter indices via replicated cursors ----
__global__ void scatter_kernel(const float2* __restrict__ pts, int* __restrict__ cur,
                               int* __restrict__ sidx, int N, int rmask) {
    int i = blockIdx.x * 256 + threadIdx.x;
    if (i >= N) return;
    int r = blockIdx.x & rmask;
    int pos = atomicAdd(&cur[r * NBINS + point_bin(pts[i])], 1);
    sidx[pos] = i;
}

// ---- main kernel: exact R7 structure (1 pt/thread, VGPR 36, 115 us) ----
__global__ __launch_bounds__(256, 4) void hashgrid_mlp_kernel(
    const float2* __restrict__ pts,
    const float2* __restrict__ table,   // [16][524288] float2
    const int*    __restrict__ sidx,    // bin-sorted point indices
    const float*  __restrict__ W1,      // [64][32]
    const float*  __restrict__ W2,      // [3][64]
    float* __restrict__ out,            // [N][3]
    int N, Scales sc)
{
    int j = blockIdx.x * 256 + threadIdx.x;
    if (j >= N) return;
    int i = sidx[j];

    float2 p = pts[i];
    float enc[32];

#pragma unroll
    for (int l = 0; l < NLV; ++l) {
        float s  = sc.s[l];
        float px = p.x * s;              // f32 mul, bitwise == reference
        float py = p.y * s;
        float fpx = floorf(px), fpy = floorf(py);
        float fx = px - fpx, fy = py - fpy;
        unsigned bx = (unsigned)(int)fpx;
        unsigned by = (unsigned)(int)fpy;
        unsigned hy0 = by * PRIME1;
        unsigned hy1 = hy0 + PRIME1;     // (by+1)*PRIME1 mod 2^32
        const float2* tl = table + (size_t)l * TBL;
        float2 f00 = tl[( bx        ^ hy0) & HMASK];
        float2 f01 = tl[( bx        ^ hy1) & HMASK];
        float2 f10 = tl[((bx + 1u)  ^ hy0) & HMASK];
        float2 f11 = tl[((bx + 1u)  ^ hy1) & HMASK];
        float gx = 1.f - fx, gy = 1.f - fy;
        float w00 = gx * gy, w01 = gx * fy, w10 = fx * gy, w11 = fx * fy;
        enc[2*l]   = w00*f00.x + w01*f01.x + w10*f10.x + w11*f11.x;
        enc[2*l+1] = w00*f00.y + w01*f01.y + w10*f10.y + w11*f11.y;
    }

    float o0 = 0.f, o1 = 0.f, o2 = 0.f;
#pragma unroll
    for (int n = 0; n < 64; ++n) {
        float h = 0.f;
#pragma unroll
        for (int k = 0; k < 32; ++k)
            h = fmaf(enc[k], W1[n*32 + k], h);   // uniform addr -> s_load
        h = fmaxf(h, 0.f);
        o0 = fmaf(h, W2[      n], o0);
        o1 = fmaf(h, W2[ 64 + n], o1);
        o2 = fmaf(h, W2[128 + n], o2);
    }
    out[3*i + 0] = o0;
    out[3*i + 1] = o1;
    out[3*i + 2] = o2;
}

// ---- fallback (round-1) if ws too small for the sort ----
__global__ __launch_bounds__(256, 4) void hashgrid_mlp_fallback(
    const float2* __restrict__ pts, const float2* __restrict__ table,
    const float* __restrict__ W1, const float* __restrict__ W2,
    float* __restrict__ out, int N, Scales sc)
{
    int i = blockIdx.x * 256 + threadIdx.x;
    if (i >= N) return;
    float2 p = pts[i];
    float enc[32];
#pragma unroll
    for (int l = 0; l < NLV; ++l) {
        float s = sc.s[l];
        float px = p.x * s, py = p.y * s;
        float fpx = floorf(px), fpy = floorf(py);
        float fx = px - fpx, fy = py - fpy;
        unsigned bx = (unsigned)(int)fpx, by = (unsigned)(int)fpy;
        unsigned hy0 = by * PRIME1, hy1 = hy0 + PRIME1;
        const float2* tl = table + (size_t)l * TBL;
        float2 f00 = tl[( bx       ^ hy0) & HMASK];
        float2 f01 = tl[( bx       ^ hy1) & HMASK];
        float2 f10 = tl[((bx + 1u) ^ hy0) & HMASK];
        float2 f11 = tl[((bx + 1u) ^ hy1) & HMASK];
        float gx = 1.f - fx, gy = 1.f - fy;
        float w00 = gx * gy, w01 = gx * fy, w10 = fx * gy, w11 = fx * fy;
        enc[2*l]   = w00*f00.x + w01*f01.x + w10*f10.x + w11*f11.x;
        enc[2*l+1] = w00*f00.y + w01*f01.y + w10*f10.y + w11*f11.y;
    }
    float o0 = 0.f, o1 = 0.f, o2 = 0.f;
#pragma unroll
    for (int n = 0; n < 64; ++n) {
        float h = 0.f;
#pragma unroll
        for (int k = 0; k < 32; ++k) h = fmaf(enc[k], W1[n*32 + k], h);
        h = fmaxf(h, 0.f);
        o0 = fmaf(h, W2[n], o0); o1 = fmaf(h, W2[64 + n], o1); o2 = fmaf(h, W2[128 + n], o2);
    }
    out[3*i] = o0; out[3*i + 1] = o1; out[3*i + 2] = o2;
}

extern "C" void kernel_launch(void* const* d_in, const int* in_sizes, int n_in,
                              void* d_out, int out_size, void* d_ws, size_t ws_size,
                              hipStream_t stream) {
    const float2* pts   = (const float2*)d_in[0];
    const float2* table = (const float2*)d_in[1];
    const float*  W1    = (const float*)d_in[2];
    const float*  W2    = (const float*)d_in[3];
    float* out = (float*)d_out;
    int N = in_sizes[0] / 2;

    // Replicate numpy: np.floor(16 * 1.447269237440378 ** arange(16)).astype(f32)
    // (level 15 is a floor boundary: 4095, NOT 4096 — host pow matches numpy).
    Scales sc;
    for (int l = 0; l < NLV; ++l)
        sc.s[l] = (float)floor(16.0 * pow(1.447269237440378, (double)l));

    int blocks = (N + 255) / 256;
    int R = 8;                                        // replica count (pow2)
    size_t need = ((size_t)R * NBINS + NBINS + N) * sizeof(int);
    if (ws_size < need) { R = 1; need = ((size_t)NBINS + NBINS + N) * sizeof(int); }

    if (ws_size >= need) {
        int* hist   = (int*)d_ws;            // R*NBINS counters -> cursors
        int* binsum = hist + R * NBINS;      // NBINS bin totals -> bin bases
        int* sidx   = binsum + NBINS;        // N sorted indices
        int binblocks = (NBINS + 255) / 256;
        hipMemsetAsync(hist, 0, (size_t)R * NBINS * sizeof(int), stream);
        hipLaunchKernelGGL(hist_kernel,    dim3(blocks),    dim3(256),  0, stream,
                           pts, hist, N, R - 1);
        hipLaunchKernelGGL(binsum_kernel,  dim3(binblocks), dim3(256),  0, stream,
                           hist, binsum, R);
        hipLaunchKernelGGL(scan_kernel,    dim3(1),         dim3(1024), 0, stream,
                           binsum, NBINS);
        hipLaunchKernelGGL(cursor_kernel,  dim3(binblocks), dim3(256),  0, stream,
                           hist, binsum, R);
        hipLaunchKernelGGL(scatter_kernel, dim3(blocks),    dim3(256),  0, stream,
                           pts, hist, sidx, N, R - 1);
        hipLaunchKernelGGL(hashgrid_mlp_kernel, dim3(blocks), dim3(256), 0, stream,
                           pts, table, sidx, W1, W2, out, N, sc);
    } else {
        hipLaunchKernelGGL(hashgrid_mlp_fallback, dim3(blocks), dim3(256), 0, stream,
                           pts, table, W1, W2, out, N, sc);
    }
}